// Round 9
// baseline (200.559 us; speedup 1.0000x reference)
//
#include <hip/hip_runtime.h>
#include <math.h>

#define BB   16
#define SS   4096
#define DD   64
#define HH   8
#define NBH  32
#define NB   64
#define NCH  512     // global chunks per batch = HH * 64

typedef __attribute__((ext_vector_type(8))) short s16x8;   // 8 bf16
typedef __attribute__((ext_vector_type(4))) short s16x4;   // 4 bf16
typedef __attribute__((ext_vector_type(4))) float f32x4;
typedef __attribute__((ext_vector_type(4))) unsigned u32x4;

static __device__ __forceinline__ unsigned short f2bf(float x) {
  union { float f; unsigned u; } a; a.f = x;
  unsigned r = a.u + 0x7fffu + ((a.u >> 16) & 1u);   // RNE
  return (unsigned short)(r >> 16);
}
static __device__ __forceinline__ float bf2f(unsigned short u) {
  union { unsigned u; float f; } a; a.u = ((unsigned)u) << 16;
  return a.f;
}
// RNE bf16 kept in bits [31:16] (same formula as f2bf, un-shifted).
static __device__ __forceinline__ unsigned bfrnd_hi(float x) {
  union { float f; unsigned u; } a; a.f = x;
  return a.u + 0x7fffu + ((a.u >> 16) & 1u);
}
// Pack two floats as bf16 pair via v_perm byte-select. Bit-identical to
// (f2bf(lo) | f2bf(hi)<<16). Builtin, NOT inline asm (cvt_pk asm banned: R12).
static __device__ __forceinline__ unsigned pack_bf(float lo, float hi) {
  return __builtin_amdgcn_perm(bfrnd_hi(hi), bfrnd_hi(lo), 0x07060302u);
}

// ---------------------------------------------------------------------------
// Kernel 0 (R17): FUSED k_conv + k_rotT. Blocks <2048 stream fp32->bf16
// conversion; blocks >=2048 transpose rotations (b = blockIdx.x-2048).
// Branch is block-uniform so the rotT barriers are safe.
// NOTE (R18 lesson): hipLaunchCooperativeKernel ABORTS under this harness's
// graph capture — cooperative mega-fusion is banned; 5 launches is the floor.
// ---------------------------------------------------------------------------
__global__ __launch_bounds__(256) void k_prep(
    const float* __restrict__ qk, const float* __restrict__ v,
    const float* __restrict__ rot,
    unsigned short* __restrict__ qb, unsigned short* __restrict__ kb,
    unsigned short* __restrict__ vb,
    unsigned short* __restrict__ rTh, unsigned short* __restrict__ rTl,
    int* __restrict__ needy_count) {
  __shared__ float slab[32][256];
  const int tid = threadIdx.x;

  if (blockIdx.x >= 2048) {
    // ---- rotT part ----
    const int b = blockIdx.x - 2048;
    if (b == 0 && tid == 0) *needy_count = 0;
    for (int st = 0; st < 2; st++) {
#pragma unroll
      for (int fr = 0; fr < 32; fr++)
        slab[fr][tid] = rot[(size_t)b * (DD * HH * NBH) +
                            (size_t)(st * 32 + fr) * 256 + tid];
      __syncthreads();
      unsigned short hi[32], lo[32];
#pragma unroll
      for (int fr = 0; fr < 32; fr++) {
        const float x = slab[fr][tid];
        const unsigned short hh = f2bf(x);
        hi[fr] = hh;
        lo[fr] = f2bf(x - bf2f(hh));
      }
      unsigned short* dh = rTh + ((size_t)b * 256 + tid) * DD + st * 32;
      unsigned short* dl = rTl + ((size_t)b * 256 + tid) * DD + st * 32;
#pragma unroll
      for (int g = 0; g < 4; g++) {
        *(s16x8*)(dh + g * 8) = *(const s16x8*)&hi[g * 8];
        *(s16x8*)(dl + g * 8) = *(const s16x8*)&lo[g * 8];
      }
      __syncthreads();
    }
    return;
  }

  // ---- conv part ----
  const int gid = blockIdx.x * 256 + tid;
  const int half = BB * SS * 4;
  const bool isV = gid >= half;
  const int id = isV ? gid - half : gid;
  const int row = id >> 2, q4 = id & 3;

  const float4* src =
      (const float4*)((isV ? v : qk) + (size_t)row * DD + q4 * 16);
  float vals[16];
#pragma unroll
  for (int g = 0; g < 4; g++) {
    const float4 a = src[g];
    vals[g * 4 + 0] = a.x; vals[g * 4 + 1] = a.y;
    vals[g * 4 + 2] = a.z; vals[g * 4 + 3] = a.w;
  }

  if (!isV) {
    float ss = 0.f;
#pragma unroll
    for (int i = 0; i < 16; i++) ss += vals[i] * vals[i];
    ss += __shfl_xor(ss, 1);
    ss += __shfl_xor(ss, 2);
    const float scl = 0.125f / (sqrtf(ss) + 1e-6f);
    unsigned short qo[16], ko[16];
#pragma unroll
    for (int i = 0; i < 16; i++) {
      qo[i] = f2bf(vals[i]);
      ko[i] = f2bf(vals[i] * scl);
    }
    unsigned short* qd = qb + (size_t)row * DD + q4 * 16;
    unsigned short* kd = kb + (size_t)row * DD + q4 * 16;
    *(s16x8*)qd = *(const s16x8*)&qo[0];
    *(s16x8*)(qd + 8) = *(const s16x8*)&qo[8];
    *(s16x8*)kd = *(const s16x8*)&ko[0];
    *(s16x8*)(kd + 8) = *(const s16x8*)&ko[8];
  } else {
    unsigned short vo[16];
#pragma unroll
    for (int i = 0; i < 16; i++) vo[i] = f2bf(vals[i]);
    unsigned short* vd = vb + (size_t)row * DD + q4 * 16;
    *(s16x8*)vd = *(const s16x8*)&vo[0];
    *(s16x8*)(vd + 8) = *(const s16x8*)&vo[8];
  }
}

// ---------------------------------------------------------------------------
// Kernel 1a (R17): MFMA LSH hash with FUSED needy fp64 fix. R15 structure
// (64-token blocks, dbuf sc, one barrier/h, 4-lane argmax) — scores/buckets
// bit-identical. Needy entries are block-local, collected in LDS; after the
// h-loop each HALF-WAVE runs k_hash_fix's exact fp64 recompute + shuffle
// argmax (same math, same li<32 structure, same tie rule).
// ---------------------------------------------------------------------------
#define MARGIN 1e-2f

__global__ __launch_bounds__(256, 4) void k_hash_mfma(
    const float* __restrict__ qk, const float* __restrict__ rot,
    const unsigned short* __restrict__ rTh,
    const unsigned short* __restrict__ rTl, int* __restrict__ bucket_local,
    float* __restrict__ buckets_out) {
  __shared__ struct __align__(16) {
    unsigned short ah[64][72];    // 9216 B
    unsigned short al[64][72];    // 9216 B
    float sc[2][64][33];          // 16896 B
    int needy[512];               // 2048 B
    int ncnt;                     // -> ~37.4 KB total, 4 blocks/CU
  } sm;
  const int b = blockIdx.x;
  const int t0 = blockIdx.y * 64;
  const int tid = threadIdx.x;
  const int w = tid >> 6, lane = tid & 63;
  const int quad = lane >> 4, l16 = lane & 15;

  if (tid == 0) sm.ncnt = 0;

  // ---- stage A hi/lo (thread = quarter token row, 16 floats) ----
  {
    const int row = tid >> 2, qf = tid & 3;
    const float4* src =
        (const float4*)(qk + ((size_t)b * SS + t0 + row) * DD + qf * 16);
#pragma unroll
    for (int gg = 0; gg < 2; gg++) {
      const float4 v0 = src[gg * 2], v1 = src[gg * 2 + 1];
      const float a[8] = {v0.x, v0.y, v0.z, v0.w, v1.x, v1.y, v1.z, v1.w};
      unsigned short hi[8], lo[8];
#pragma unroll
      for (int e = 0; e < 8; e++) {
        const unsigned short hh = f2bf(a[e]);
        hi[e] = hh;
        lo[e] = f2bf(a[e] - bf2f(hh));
      }
      *(s16x8*)&sm.ah[row][qf * 16 + gg * 8] = *(const s16x8*)hi;
      *(s16x8*)&sm.al[row][qf * 16 + gg * 8] = *(const s16x8*)lo;
    }
  }
  __syncthreads();

  // ---- hoist A-frags (wave w owns token rows w*16..w*16+15) ----
  s16x8 Ah[2], Al[2];
#pragma unroll
  for (int ks = 0; ks < 2; ks++) {
    Ah[ks] = *(const s16x8*)&sm.ah[w * 16 + l16][ks * 32 + quad * 8];
    Al[ks] = *(const s16x8*)&sm.al[w * 16 + l16][ks * 32 + quad * 8];
  }

#pragma unroll 1
  for (int h = 0; h < HH; h++) {
    const int p = h & 1;
#pragma unroll
    for (int nt = 0; nt < 2; nt++) {
      const size_t rrow = (((size_t)b * HH + h) * 32 + nt * 16 + l16) * DD;
      s16x8 Bh2[2], Bl2[2];
#pragma unroll
      for (int ks = 0; ks < 2; ks++) {
        Bh2[ks] = *(const s16x8*)&rTh[rrow + ks * 32 + quad * 8];
        Bl2[ks] = *(const s16x8*)&rTl[rrow + ks * 32 + quad * 8];
      }
      f32x4 acc = (f32x4){0.f, 0.f, 0.f, 0.f};
#pragma unroll
      for (int ks = 0; ks < 2; ks++) {
        acc = __builtin_amdgcn_mfma_f32_16x16x32_bf16(Al[ks], Bl2[ks], acc, 0, 0, 0);
        acc = __builtin_amdgcn_mfma_f32_16x16x32_bf16(Al[ks], Bh2[ks], acc, 0, 0, 0);
        acc = __builtin_amdgcn_mfma_f32_16x16x32_bf16(Ah[ks], Bl2[ks], acc, 0, 0, 0);
        acc = __builtin_amdgcn_mfma_f32_16x16x32_bf16(Ah[ks], Bh2[ks], acc, 0, 0, 0);
      }
#pragma unroll
      for (int r = 0; r < 4; r++)
        sm.sc[p][w * 16 + quad * 4 + r][nt * 16 + l16] = acc[r];
    }
    __syncthreads();

    // ---- 4-lane argmax: quad = segment {+lo,+hi,-lo,-hi}, 16 steps ----
    {
      const int tloc = w * 16 + l16;           // token within block's 64
      const float sgn = (quad >= 2) ? -1.0f : 1.0f;
      const float* rowp = &sm.sc[p][tloc][(quad & 1) * 16];
      float best = -3.0e38f, second = -3.0e38f;
      int bi = quad * 16;
#pragma unroll 8
      for (int i = 0; i < 16; i++) {
        const float vv = sgn * rowp[i];
        if (vv > best) { second = best; best = vv; bi = quad * 16 + i; }
        else if (vv > second) second = vv;
      }
      // merge level 1: xor 16 (seg pairs 0-1 and 2-3)
      {
        const float ob = __shfl_xor(best, 16);
        const float os = __shfl_xor(second, 16);
        const int obi = __shfl_xor(bi, 16);
        const float ms = fmaxf(fminf(best, ob), fmaxf(second, os));
        const bool partnerLower = (lane & 16) != 0;
        if (partnerLower ? (ob >= best) : (ob > best)) { best = ob; bi = obi; }
        second = ms;
      }
      // merge level 2: xor 32 (+half vs -half; + scanned "first")
      {
        const float ob = __shfl_xor(best, 32);
        const float os = __shfl_xor(second, 32);
        const int obi = __shfl_xor(bi, 32);
        const float ms = fmaxf(fminf(best, ob), fmaxf(second, os));
        const bool partnerLower = (lane & 32) != 0;
        if (partnerLower ? (ob >= best) : (ob > best)) { best = ob; bi = obi; }
        second = ms;
      }
      if (quad == 0) {
        const int t = t0 + tloc;
        bucket_local[((size_t)b * HH + h) * SS + t] = bi;
        buckets_out[(size_t)b * (HH * SS) + (size_t)h * SS + t] =
            (float)(h * NB + bi);
        if (best - second <= MARGIN) {
          const int slot = atomicAdd(&sm.ncnt, 1);
          sm.needy[slot] = (h << 6) | tloc;
        }
      }
    }
    // no trailing barrier: next h writes sc[1-p]; WAR on sc[p] is covered
    // by the barrier inside iteration h+1.
  }
  __syncthreads();   // needy list complete; scan global writes drained

  // ---- fused fp64 fix (identical math/structure to old k_hash_fix) ----
  const int nfix = sm.ncnt;
  const int hwid = tid >> 5;     // half-wave id 0..7
  const int li = tid & 31;
  for (int idx = hwid; idx < nfix; idx += 8) {
    const int code = sm.needy[idx];
    const int h2 = code >> 6, tloc = code & 63;
    const int t = t0 + tloc;
    const float* qrow = qk + ((size_t)b * SS + t) * DD;
    const float* rcol = rot + ((size_t)b * DD * HH + h2) * NBH + li;

    double acc = 0.0;
#pragma unroll 8
    for (int f = 0; f < DD; f++)
      acc += (double)qrow[f] * (double)rcol[(size_t)f * (HH * NBH)];

    double bv = acc;
    int bi = li;
    if (-acc > bv) { bv = -acc; bi = li + 32; }
#pragma unroll
    for (int off = 1; off < 32; off <<= 1) {
      const double ov = __shfl_xor(bv, off);
      const int oi = __shfl_xor(bi, off);
      if (ov > bv || (ov == bv && oi < bi)) { bv = ov; bi = oi; }
    }
    if (li == 0) {
      bucket_local[((size_t)b * HH + h2) * SS + t] = bi;
      buckets_out[(size_t)b * (HH * SS) + (size_t)h2 * SS + t] =
          (float)(h2 * NB + bi);
    }
  }
}

// ---------------------------------------------------------------------------
// Kernel 1b: exact fp64 recompute for near-ties (fallback path only now).
// ---------------------------------------------------------------------------
__global__ __launch_bounds__(256) void k_hash_fix(
    const float* __restrict__ qk, const float* __restrict__ rot,
    const int* __restrict__ needy_list, const int* __restrict__ needy_count,
    int* __restrict__ bucket_local, float* __restrict__ buckets_out) {
  const int n = *needy_count;
  const int hw = (blockIdx.x * 256 + (int)threadIdx.x) >> 5;
  const int li = threadIdx.x & 31;
  const int nhw = gridDim.x * 8;

  for (int idx = hw; idx < n; idx += nhw) {
    const int code = needy_list[idx];
    const int t = code & 4095;
    const int bh = code >> 12;
    const int b = bh >> 3, h = bh & 7;

    const float* qrow = qk + ((size_t)b * SS + t) * DD;
    const float* rcol = rot + ((size_t)b * DD * HH + h) * NBH + li;

    double acc = 0.0;
#pragma unroll 8
    for (int f = 0; f < DD; f++)
      acc += (double)qrow[f] * (double)rcol[(size_t)f * (HH * NBH)];

    double bv = acc;
    int bi = li;
    if (-acc > bv) { bv = -acc; bi = li + 32; }
#pragma unroll
    for (int off = 1; off < 32; off <<= 1) {
      const double ov = __shfl_xor(bv, off);
      const int oi = __shfl_xor(bi, off);
      if (ov > bv || (ov == bv && oi < bi)) { bv = ov; bi = oi; }
    }
    if (li == 0) {
      bucket_local[((size_t)b * HH + h) * SS + t] = bi;
      buckets_out[(size_t)b * (HH * SS) + (size_t)h * SS + t] =
          (float)(h * NB + bi);
    }
  }
}

// ---------------------------------------------------------------------------
// Kernel 2: parallel stable counting-rank sort per (b,h). R17: cnt rows
// padded to 260 B and pfx rows to 258 shorts (bank spread); ipos dropped.
// ---------------------------------------------------------------------------
__global__ __launch_bounds__(256) void k_sort(
    const int* __restrict__ bucket_local, int* __restrict__ sort_t,
    int* __restrict__ ipos) {
  __shared__ unsigned short lb[SS];
  __shared__ __align__(16) unsigned char cnt[NB][260];
  __shared__ __align__(16) unsigned short pfx[NB][258];
  __shared__ int part[NB][4];
  __shared__ int tot[NB];
  __shared__ int base[NB];

  const int bh = blockIdx.x;
  const int tid = threadIdx.x;
  const int* src = bucket_local + (size_t)bh * SS;

  int* czero = (int*)&cnt[0][0];
#pragma unroll
  for (int i = 0; i < 17; i++) {
    const int o = tid + i * 256;
    if (o < (NB * 260) / 4) czero[o] = 0;
  }
  __syncthreads();

#pragma unroll
  for (int i = 0; i < 16; i++) {
    const int t = tid * 16 + i;
    const int v = src[t];
    lb[t] = (unsigned short)v;
    cnt[v][tid]++;
  }
  __syncthreads();

  {
    const int bk = tid & 63, sg = tid >> 6;
    int s = 0;
#pragma unroll 8
    for (int i = 0; i < 64; i++) s += cnt[bk][sg * 64 + i];
    part[bk][sg] = s;
  }
  __syncthreads();
  if (tid < NB) tot[tid] = part[tid][0] + part[tid][1] + part[tid][2] + part[tid][3];
  __syncthreads();
  if (tid == 0) {
    int r = 0;
    for (int i = 0; i < NB; i++) { base[i] = r; r += tot[i]; }
  }
  __syncthreads();
  {
    const int bk = tid & 63, sg = tid >> 6;
    int run = base[bk];
    for (int s = 0; s < sg; s++) run += part[bk][s];
#pragma unroll 8
    for (int i = 0; i < 64; i++) {
      const int th = sg * 64 + i;
      pfx[bk][th] = (unsigned short)run;
      run += cnt[bk][th];
    }
  }
  __syncthreads();
  int* st = sort_t + (size_t)bh * SS;
#pragma unroll
  for (int i = 0; i < 16; i++) {
    const int t = tid * 16 + i;
    const int bk = lb[t];
    const int pos = pfx[bk][tid]++;
    st[pos] = t;
  }
  (void)ipos;
}

// ---------------------------------------------------------------------------
// Kernel 3: chunked attention (R14, unchanged — 62.4us measured).
// ---------------------------------------------------------------------------
__global__ __launch_bounds__(256, 4) void k_attn2(
    const unsigned short* __restrict__ qb, const unsigned short* __restrict__ kbg,
    const unsigned short* __restrict__ vbg, const int* __restrict__ sort_t,
    unsigned short* __restrict__ so, float* __restrict__ lse_u) {
  const int blk = blockIdx.x;
  const int b = blk >> 9;
  const int c = blk & 511;
  const int h = c >> 6, cc = c & 63;
  const int cp = (c + 511) & 511;
  const int hp = cp >> 6, ccp = cp & 63;

  __shared__ struct __align__(16) {
    union {
      unsigned short kb[128][72];   // K during QK^T (18432 B)
      unsigned short p[64][136];    // probs during PV (17408 B)
      float olds[64][68];           // O f32 after PV (17408 B)
    } kp;
    unsigned short vsT[64][136];    // V^T: [feature][token], 17408 B
    int tk[128];                    // 512 B -> total 36352
  } sm;

  const int tid = threadIdx.x;
  const int w = tid >> 6;
  const int lane = tid & 63;
  const int quad = lane >> 4;
  const int l16 = lane & 15;

  if (tid < 128) {
    const size_t srci = (tid < 64)
        ? (((size_t)b * HH + h) * SS + cc * 64 + tid)
        : (((size_t)b * HH + hp) * SS + ccp * 64 + (tid - 64));
    sm.tk[tid] = sort_t[srci];
  }
  __syncthreads();

  // ---- stage K row-major (2 thr/row) ----
  {
    const int j = tid >> 1, hf = tid & 1;
    const int trow = sm.tk[j];
    const s16x8* ksrc = (const s16x8*)(kbg + ((size_t)b * SS + trow) * DD + hf * 32);
    s16x8 kr[4];
#pragma unroll
    for (int g = 0; g < 4; g++) kr[g] = ksrc[g];
#pragma unroll
    for (int g = 0; g < 4; g++)
      *(s16x8*)&sm.kp.kb[j][hf * 32 + g * 8] = kr[g];
  }
  // ---- stage V transposed (thread = 4 tokens x 8 features, v_perm pack) ----
  {
    const int fg = tid >> 5;          // 0..7  feature group (8 feats)
    const int tg = (tid & 31) << 2;   // 0,4,...,124 token base
    const unsigned short* vb_b = vbg + (size_t)b * SS * DD + fg * 8;
    const u32x4 a0v = *(const u32x4*)(vb_b + (size_t)sm.tk[tg + 0] * DD);
    const u32x4 a1v = *(const u32x4*)(vb_b + (size_t)sm.tk[tg + 1] * DD);
    const u32x4 a2v = *(const u32x4*)(vb_b + (size_t)sm.tk[tg + 2] * DD);
    const u32x4 a3v = *(const u32x4*)(vb_b + (size_t)sm.tk[tg + 3] * DD);
#pragma unroll
    for (int j = 0; j < 4; j++) {
      uint2 ev, ov;
      ev.x = __builtin_amdgcn_perm(a1v[j], a0v[j], 0x05040100u);
      ev.y = __builtin_amdgcn_perm(a3v[j], a2v[j], 0x05040100u);
      ov.x = __builtin_amdgcn_perm(a1v[j], a0v[j], 0x07060302u);
      ov.y = __builtin_amdgcn_perm(a3v[j], a2v[j], 0x07060302u);
      *(uint2*)&sm.vsT[fg * 8 + 2 * j][tg] = ev;
      *(uint2*)&sm.vsT[fg * 8 + 2 * j + 1][tg] = ov;
    }
  }
  // ---- Q B-frags direct from global (tk valid after first barrier) ----
  const int tq = sm.tk[w * 16 + l16];
  const unsigned short* qrowp = qb + ((size_t)b * SS + tq) * DD;
  const s16x8 a0 = *(const s16x8*)(qrowp + quad * 8);
  const s16x8 a1 = *(const s16x8*)(qrowp + 32 + quad * 8);
  __syncthreads();

  // ---- QK^T swapped: acc[nt] holds S[q = w*16+l16][k = nt*16+quad*4+r] ----
  f32x4 acc[8];
#pragma unroll
  for (int nt = 0; nt < 8; nt++) acc[nt] = (f32x4){0.f, 0.f, 0.f, 0.f};
#pragma unroll
  for (int nt = 0; nt < 8; nt++) {
    const s16x8 b0 = *(const s16x8*)&sm.kp.kb[nt * 16 + l16][quad * 8];
    const s16x8 b1 = *(const s16x8*)&sm.kp.kb[nt * 16 + l16][32 + quad * 8];
    acc[nt] = __builtin_amdgcn_mfma_f32_16x16x32_bf16(b0, a0, acc[nt], 0, 0, 0);
    acc[nt] = __builtin_amdgcn_mfma_f32_16x16x32_bf16(b1, a1, acc[nt], 0, 0, 0);
  }

  // ---- self-mask (index-based, S^T layout) ----
  {
    const bool dm = (quad == (l16 >> 2));
    const int rm = l16 & 3;
#pragma unroll
    for (int nt = 0; nt < 4; nt++)
      if (nt == w) {
#pragma unroll
        for (int r = 0; r < 4; r++)
          if (dm && rm == r) acc[nt][r] = -50000.0f;
      }
  }
  if (cc == 0) {     // look-back crosses hash rounds: token ids can repeat
#pragma unroll
    for (int nt = 4; nt < 8; nt++)
#pragma unroll
      for (int r = 0; r < 4; r++)
        if (sm.tk[nt * 16 + quad * 4 + r] == tq) acc[nt][r] = -50000.0f;
  }

  // ---- scalar row softmax (in-lane 32 + shfl 16,32) ----
  float mv[8];
#pragma unroll
  for (int nt = 0; nt < 8; nt++)
    mv[nt] = fmaxf(fmaxf(acc[nt][0], acc[nt][1]), fmaxf(acc[nt][2], acc[nt][3]));
  float m = fmaxf(fmaxf(fmaxf(mv[0], mv[1]), fmaxf(mv[2], mv[3])),
                  fmaxf(fmaxf(mv[4], mv[5]), fmaxf(mv[6], mv[7])));
  m = fmaxf(m, __shfl_xor(m, 16));
  m = fmaxf(m, __shfl_xor(m, 32));

  float sv[8];
#pragma unroll
  for (int nt = 0; nt < 8; nt++) {
#pragma unroll
    for (int r = 0; r < 4; r++) acc[nt][r] = __expf(acc[nt][r] - m);
    sv[nt] = (acc[nt][0] + acc[nt][1]) + (acc[nt][2] + acc[nt][3]);
  }
  float s = ((sv[0] + sv[1]) + (sv[2] + sv[3])) +
            ((sv[4] + sv[5]) + (sv[6] + sv[7]));
  s += __shfl_xor(s, 16);
  s += __shfl_xor(s, 32);
  const float inv = 1.0f / s;
  const float lse = __logf(s) + m;

  if (quad == 0)
    lse_u[((size_t)b * SS + tq) * HH + h] = lse;

  __syncthreads();   // all kb reads done -> safe to overwrite with p

  // ---- stage probs bf16: lane writes its 4 consecutive k-cols per nt ----
  {
    const int prow = w * 16 + l16;
#pragma unroll
    for (int nt = 0; nt < 8; nt++) {
      uint2 pv;
      pv.x = pack_bf(acc[nt][0] * inv, acc[nt][1] * inv);
      pv.y = pack_bf(acc[nt][2] * inv, acc[nt][3] * inv);
      *(uint2*)&sm.kp.p[prow][nt * 16 + quad * 4] = pv;
    }
  }
  __syncthreads();

  // ---- PV as O^T = V^T * P^T (both operands ds_read_b128) ----
  f32x4 o[4];
#pragma unroll
  for (int nt = 0; nt < 4; nt++) o[nt] = (f32x4){0.f, 0.f, 0.f, 0.f};
  const unsigned short* vrow = &sm.vsT[w * 16 + l16][0];
#pragma unroll
  for (int kc = 0; kc < 4; kc++) {
    const s16x8 av = *(const s16x8*)(vrow + kc * 32 + quad * 8);
#pragma unroll
    for (int nt = 0; nt < 4; nt++) {
      const s16x8 bp = *(const s16x8*)&sm.kp.p[nt * 16 + l16][kc * 32 + quad * 8];
      o[nt] = __builtin_amdgcn_mfma_f32_16x16x32_bf16(av, bp, o[nt], 0, 0, 0);
    }
  }

  __syncthreads();   // all p reads done -> safe to overwrite with olds

  // ---- park O in LDS f32: lane holds q = nt*16+l16, f = w*16+quad*4..+3 ----
#pragma unroll
  for (int nt = 0; nt < 4; nt++)
    *(f32x4*)&sm.kp.olds[nt * 16 + l16][w * 16 + quad * 4] = o[nt];
  __syncthreads();

  // ---- coalesced store: 4 threads/token emit the full 128B row ----
  {
    const int q = tid >> 2, qt = tid & 3;
    const int t = sm.tk[q];
    float vals[16];
    *(f32x4*)&vals[0]  = *(const f32x4*)&sm.kp.olds[q][qt * 16 + 0];
    *(f32x4*)&vals[4]  = *(const f32x4*)&sm.kp.olds[q][qt * 16 + 4];
    *(f32x4*)&vals[8]  = *(const f32x4*)&sm.kp.olds[q][qt * 16 + 8];
    *(f32x4*)&vals[12] = *(const f32x4*)&sm.kp.olds[q][qt * 16 + 12];
    unsigned pk[8];
#pragma unroll
    for (int g = 0; g < 8; g++) pk[g] = pack_bf(vals[2 * g], vals[2 * g + 1]);
    unsigned short* dst =
        so + (((size_t)b * SS + t) * HH + h) * DD + qt * 16;
    *(uint4*)dst = *(const uint4*)&pk[0];
    *(uint4*)(dst + 8) = *(const uint4*)&pk[4];
  }
}

// ---------------------------------------------------------------------------
// Kernel 4: streaming combine over hashes (R16 vectorized, unchanged).
// ---------------------------------------------------------------------------
__global__ __launch_bounds__(256) void k_combine2(
    const unsigned short* __restrict__ so, const float* __restrict__ lse_u,
    float* __restrict__ out) {
  const size_t idx = (size_t)blockIdx.x * 256 + threadIdx.x;
  const int fg = (int)(idx & 7);           // feature group of 8
  const size_t bt = idx >> 3;

  const float4 l0 = *(const float4*)(lse_u + bt * HH);
  const float4 l1 = *(const float4*)(lse_u + bt * HH + 4);
  const float l[HH] = {l0.x, l0.y, l0.z, l0.w, l1.x, l1.y, l1.z, l1.w};
  float m = l[0];
#pragma unroll
  for (int h = 1; h < HH; h++) m = fmaxf(m, l[h]);

  float den = 0.f;
  float num[8];
#pragma unroll
  for (int e = 0; e < 8; e++) num[e] = 0.f;
#pragma unroll
  for (int h = 0; h < HH; h++) {
    const float wgt = __expf(l[h] - m);
    den += wgt;
    const s16x8 v = *(const s16x8*)(so + (bt * HH + h) * DD + fg * 8);
#pragma unroll
    for (int e = 0; e < 8; e++)
      num[e] += wgt * bf2f((unsigned short)v[e]);
  }

  float4 o0, o1;
  o0.x = num[0] / den; o0.y = num[1] / den;
  o0.z = num[2] / den; o0.w = num[3] / den;
  o1.x = num[4] / den; o1.y = num[5] / den;
  o1.z = num[6] / den; o1.w = num[7] / den;
  float* dst = out + bt * DD + fg * 8;
  *(float4*)dst = o0;
  *(float4*)(dst + 4) = o1;
}

// ---------------------------------------------------------------------------
// Fallback-path hash (R8's fp32) + atomic attention (R1-proven).
// ---------------------------------------------------------------------------
__global__ __launch_bounds__(256, 2) void k_hash_f32(
    const float* __restrict__ qk, const float* __restrict__ rot,
    int* __restrict__ bucket_local, float* __restrict__ buckets_out,
    int* __restrict__ needy_list, int* __restrict__ needy_count) {
  __shared__ float lb[128 * 65];
  const int b = blockIdx.x;
  const int t0 = blockIdx.y * 128;
  const int tid = threadIdx.x;

  {
    const int row = tid >> 1, hf = (tid & 1) * 32;
    const float4* src =
        (const float4*)(qk + ((size_t)b * SS + t0 + row) * DD + hf);
    float* dst = &lb[row * 65 + hf];
#pragma unroll
    for (int g = 0; g < 8; g++) {
      const float4 vv = src[g];
      dst[g * 4 + 0] = vv.x; dst[g * 4 + 1] = vv.y;
      dst[g * 4 + 2] = vv.z; dst[g * 4 + 3] = vv.w;
    }
  }
  __syncthreads();

  const int w = tid >> 6;
  const int l = tid & 63;
  const int hb = __builtin_amdgcn_readfirstlane(w);

  for (int hp = 0; hp < 2; hp++) {
    const int h = hb + hp * 4;
    const float* rbase = rot + ((size_t)b * DD * HH + h) * NBH;
    const size_t rstride = HH * NBH;

    float acc0[NBH], acc1[NBH];
#pragma unroll
    for (int i = 0; i < NBH; i++) { acc0[i] = 0.f; acc1[i] = 0.f; }

    float4 bufA[8], bufB[8];
#pragma unroll
    for (int i4 = 0; i4 < 8; i4++) bufA[i4] = ((const float4*)rbase)[i4];

    for (int f = 0; f < DD; f += 2) {
      {
        const float4* r4 = (const float4*)(rbase + (size_t)(f + 1) * rstride);
#pragma unroll
        for (int i4 = 0; i4 < 8; i4++) bufB[i4] = r4[i4];
      }
      {
        const float q0 = lb[l * 65 + f];
        const float q1 = lb[(l + 64) * 65 + f];
#pragma unroll
        for (int i4 = 0; i4 < 8; i4++) {
          const float4 rv = bufA[i4];
          acc0[i4*4+0] = fmaf(q0, rv.x, acc0[i4*4+0]);
          acc0[i4*4+1] = fmaf(q0, rv.y, acc0[i4*4+1]);
          acc0[i4*4+2] = fmaf(q0, rv.z, acc0[i4*4+2]);
          acc0[i4*4+3] = fmaf(q0, rv.w, acc0[i4*4+3]);
          acc1[i4*4+0] = fmaf(q1, rv.x, acc1[i4*4+0]);
          acc1[i4*4+1] = fmaf(q1, rv.y, acc1[i4*4+1]);
          acc1[i4*4+2] = fmaf(q1, rv.z, acc1[i4*4+2]);
          acc1[i4*4+3] = fmaf(q1, rv.w, acc1[i4*4+3]);
        }
      }
      if (f + 2 < DD) {
        const float4* r4 = (const float4*)(rbase + (size_t)(f + 2) * rstride);
#pragma unroll
        for (int i4 = 0; i4 < 8; i4++) bufA[i4] = r4[i4];
      }
      {
        const float q0 = lb[l * 65 + f + 1];
        const float q1 = lb[(l + 64) * 65 + f + 1];
#pragma unroll
        for (int i4 = 0; i4 < 8; i4++) {
          const float4 rv = bufB[i4];
          acc0[i4*4+0] = fmaf(q0, rv.x, acc0[i4*4+0]);
          acc0[i4*4+1] = fmaf(q0, rv.y, acc0[i4*4+1]);
          acc0[i4*4+2] = fmaf(q0, rv.z, acc0[i4*4+2]);
          acc0[i4*4+3] = fmaf(q0, rv.w, acc0[i4*4+3]);
          acc1[i4*4+0] = fmaf(q1, rv.x, acc1[i4*4+0]);
          acc1[i4*4+1] = fmaf(q1, rv.y, acc1[i4*4+1]);
          acc1[i4*4+2] = fmaf(q1, rv.z, acc1[i4*4+2]);
          acc1[i4*4+3] = fmaf(q1, rv.w, acc1[i4*4+3]);
        }
      }
    }

#pragma unroll
    for (int tok = 0; tok < 2; tok++) {
      const float* acc = tok ? acc1 : acc0;
      float best = -3.0e38f, second = -3.0e38f;
      int bi = 0;
#pragma unroll
      for (int i = 0; i < 64; i++) {
        const float vv = (i < NBH) ? acc[i] : -acc[i - NBH];
        if (vv > best) { second = best; best = vv; bi = i; }
        else if (vv > second) { second = vv; }
      }
      const int t = t0 + tok * 64 + l;
      bucket_local[((size_t)b * HH + h) * SS + t] = bi;
      buckets_out[(size_t)b * (HH * SS) + (size_t)h * SS + t] =
          (float)(h * NB + bi);
      if (best - second <= MARGIN) {
        const int slot = atomicAdd(needy_count, 1);
        needy_list[slot] = (((b << 3) | h) << 12) | t;
      }
    }
  }
}

__global__ __launch_bounds__(256) void k_attn_atomic(
    const float* __restrict__ qk, const float* __restrict__ v,
    const int* __restrict__ sort_t, float* __restrict__ num,
    float* __restrict__ den) {
  const int blk = blockIdx.x;
  const int b = blk >> 9;
  const int c = blk & 511;
  const int h = c >> 6, cc = c & 63;
  const int cp = (c + 511) & 511;
  const int hp = cp >> 6, ccp = cp & 63;

  __shared__ union {
    struct {
      float qt[DD * 64];
      float kt[DD * 128];
      int   tq[64];
      int   tk[128];
      float nrm[128];
      float red[16 * 64];
      float rmax[64];
      float rsum[64];
    } a;
    struct {
      float pt[128 * 64];
      float vs[128 * 64];
    } p;
  } sm;

  const int tid = threadIdx.x;

  if (tid < 64)
    sm.a.tq[tid] = sort_t[((size_t)b * HH + h) * SS + cc * 64 + tid];
  if (tid >= 128) {
    const int j = tid - 128;
    const size_t src = (j < 64) ? (((size_t)b * HH + h) * SS + cc * 64 + j)
                                : (((size_t)b * HH + hp) * SS + ccp * 64 + (j - 64));
    sm.a.tk[j] = sort_t[src];
  }
  if (tid >= 64 && tid < 192) sm.a.nrm[tid - 64] = 0.f;
  __syncthreads();

  {
    const int qi = tid >> 2, qq = tid & 3;
    const float4* qsrc =
        (const float4*)(qk + ((size_t)b * SS + sm.a.tq[qi]) * DD) + qq * 4;
#pragma unroll
    for (int k4 = 0; k4 < 4; k4++) {
      float4 val = qsrc[k4];
      const int f = qq * 16 + k4 * 4;
      sm.a.qt[(f + 0) * 64 + qi] = val.x;
      sm.a.qt[(f + 1) * 64 + qi] = val.y;
      sm.a.qt[(f + 2) * 64 + qi] = val.z;
      sm.a.qt[(f + 3) * 64 + qi] = val.w;
    }
    const int j = tid >> 1, hhf = tid & 1;
    const float4* ksrc =
        (const float4*)(qk + ((size_t)b * SS + sm.a.tk[j]) * DD) + hhf * 8;
    float ss = 0.f;
#pragma unroll
    for (int k4 = 0; k4 < 8; k4++) {
      float4 val = ksrc[k4];
      const int f = hhf * 32 + k4 * 4;
      sm.a.kt[(f + 0) * 128 + j] = val.x;
      sm.a.kt[(f + 1) * 128 + j] = val.y;
      sm.a.kt[(f + 2) * 128 + j] = val.z;
      sm.a.kt[(f + 3) * 128 + j] = val.w;
      ss += val.x * val.x + val.y * val.y + val.z * val.z + val.w * val.w;
    }
    atomicAdd(&sm.a.nrm[j], ss);
  }
  __syncthreads();
  if (tid < 128) {
    const float n = sqrtf(sm.a.nrm[tid]) + 1e-6f;
    sm.a.nrm[tid] = 0.125f / n;
  }
  float4 vreg[8];
  {
    const int j = tid >> 1, hhf = tid & 1;
    const float4* vsrc =
        (const float4*)(v + ((size_t)b * SS + sm.a.tk[j]) * DD) + hhf * 8;
#pragma unroll
    for (int k4 = 0; k4 < 8; k4++) vreg[k4] = vsrc[k4];
  }
  __syncthreads();

  const int qi0 = (tid & 15) * 4;
  const int j0g = (tid >> 4) * 8;
  const int kg = tid >> 4;
  float acc[4][8];
#pragma unroll
  for (int i = 0; i < 4; i++)
#pragma unroll
    for (int j = 0; j < 8; j++) acc[i][j] = 0.f;

#pragma unroll 8
  for (int f = 0; f < DD; f++) {
    float4 qv = *(const float4*)&sm.a.qt[f * 64 + qi0];
    float4 k0 = *(const float4*)&sm.a.kt[f * 128 + j0g];
    float4 k1 = *(const float4*)&sm.a.kt[f * 128 + j0g + 4];
    float qa[4] = {qv.x, qv.y, qv.z, qv.w};
    float ka[8] = {k0.x, k0.y, k0.z, k0.w, k1.x, k1.y, k1.z, k1.w};
#pragma unroll
    for (int i = 0; i < 4; i++)
#pragma unroll
      for (int j = 0; j < 8; j++) acc[i][j] = fmaf(qa[i], ka[j], acc[i][j]);
  }

  int tqr[4];
#pragma unroll
  for (int i = 0; i < 4; i++) tqr[i] = sm.a.tq[qi0 + i];
  int tkr[8]; float scl[8];
#pragma unroll
  for (int j = 0; j < 8; j++) {
    tkr[j] = sm.a.tk[j0g + j];
    scl[j] = sm.a.nrm[j0g + j];
  }
#pragma unroll
  for (int i = 0; i < 4; i++)
#pragma unroll
    for (int j = 0; j < 8; j++) {
      const float dv = acc[i][j] * scl[j];
      acc[i][j] = (tqr[i] == tkr[j]) ? -50000.0f : dv;
    }

  float pmax[4];
#pragma unroll
  for (int i = 0; i < 4; i++) {
    float m = acc[i][0];
#pragma unroll
    for (int j = 1; j < 8; j++) m = fmaxf(m, acc[i][j]);
    pmax[i] = m;
  }
#pragma unroll
  for (int i = 0; i < 4; i++) sm.a.red[kg * 64 + qi0 + i] = pmax[i];
  __syncthreads();
  if (tid < 64) {
    float m = -3.0e38f;
#pragma unroll
    for (int g = 0; g < 16; g++) m = fmaxf(m, sm.a.red[g * 64 + tid]);
    sm.a.rmax[tid] = m;
  }
  __syncthreads();
  float psum[4];
#pragma unroll
  for (int i = 0; i < 4; i++) {
    const float rm = sm.a.rmax[qi0 + i];
    float s = 0.f;
#pragma unroll
    for (int j = 0; j < 8; j++) {
      const float e = __expf(acc[i][j] - rm);
      acc[i][j] = e;
      s += e;
    }
    psum[i] = s;
  }
#pragma unroll
  for (int i = 0; i < 4; i++) sm.a.red[kg * 64 + qi0 + i] = psum[i];
  __syncthreads();
  if (tid < 64) {
    float s = 0.f;
#pragma unroll
    for (int g = 0; g < 16; g++) s += sm.a.red[g * 64 + tid];
    sm.a.rsum[tid] = s;
  }
  __syncthreads();
  float lse[4], isum[4];
#pragma unroll
  for (int i = 0; i < 4; i++) {
    const float rm = sm.a.rmax[qi0 + i];
    const float s = sm.a.rsum[qi0 + i];
    isum[i] = 1.0f / s;
    lse[i] = __logf(s) + rm;
  }
  __syncthreads();

#pragma unroll
  for (int j = 0; j < 8; j++)
#pragma unroll
    for (int i = 0; i < 4; i++)
      sm.p.pt[(j0g + j) * 64 + qi0 + i] = acc[i][j] * isum[i];
  {
    const int j = tid >> 1, hhf = tid & 1;
#pragma unroll
    for (int k4 = 0; k4 < 8; k4++)
      *(float4*)&sm.p.vs[j * 64 + hhf * 32 + k4 * 4] = vreg[k4];
  }
  __syncthreads();

  const int f0 = (tid >> 4) * 4;
  float o[4][4];
#pragma unroll
  for (int i = 0; i < 4; i++)
#pragma unroll
    for (int j = 0; j < 4; j++) o[i][j] = 0.f;

#pragma unroll 8
  for (int j = 0; j < 128; j++) {
    float4 pv = *(const float4*)&sm.p.pt[j * 64 + qi0];
    float4 vv = *(const float4*)&sm.p.vs[j * 64 + f0];
    float pa[4] = {pv.x, pv.y, pv.z, pv.w};
    float va[4] = {vv.x, vv.y, vv.z, vv.w};
#pragma unroll
    for (int i = 0; i < 4; i++)
#pragma unroll
      for (int j2 = 0; j2 < 4; j2++) o[i][j2] = fmaf(pa[i], va[j2], o[i][j2]);
  }

#pragma unroll
  for (int i = 0; i < 4; i++) {
    const float w = __expf(lse[i]);
    float* dst = num + ((size_t)b * SS + tqr[i]) * DD + f0;
#pragma unroll
    for (int j = 0; j < 4; j++) atomicAdd(dst + j, o[i][j] * w);
    if (kg == 0) atomicAdd(den + (size_t)b * SS + tqr[i], w);
  }
}

__global__ __launch_bounds__(256) void k_final(float* __restrict__ o,
                                               const float* __restrict__ den) {
  const size_t i = (size_t)blockIdx.x * 256 + threadIdx.x;
  o[i] = o[i] / den[i >> 6];
}

extern "C" void kernel_launch(void* const* d_in, const int* in_sizes, int n_in,
                              void* d_out, int out_size, void* d_ws,
                              size_t ws_size, hipStream_t stream) {
  const float* qk  = (const float*)d_in[0];
  const float* v   = (const float*)d_in[1];
  const float* rot = (const float*)d_in[2];

  float* out_attn = (float*)d_out;                      // B*S*D floats
  float* buckets_out = out_attn + (size_t)BB * SS * DD; // B*H*S floats

  const size_t BHS = (size_t)BB * HH * SS;              // 524288
  const size_t BSD = (size_t)BB * SS * DD;              // 4194304
  const size_t RT  = (size_t)BB * HH * 32 * DD;         // 262144
  int* bucket_local = (int*)d_ws;
  int* sort_t = bucket_local + BHS;                     // doubles as needy_list
  int* ipos = sort_t + BHS;                             // ipos[0] = needy_count
  float* lse_u = (float*)(ipos + BHS);                  // [b][t][h]
  unsigned short* qb16 = (unsigned short*)(lse_u + BHS);
  unsigned short* kb16 = qb16 + BSD;
  unsigned short* vb16 = kb16 + BSD;
  unsigned short* so_u = vb16 + BSD;                    // [b][t][h][f] bf16
  unsigned short* rTh = so_u + BHS * DD;
  unsigned short* rTl = rTh + RT;

  const size_t NEED2 =
      4 * BHS * 4 + 3 * BSD * 2 + BHS * DD * 2 + 2 * RT * 2;  // ~101.7 MB

  if (ws_size >= NEED2) {
    k_prep<<<2048 + BB, 256, 0, stream>>>(qk, v, rot, qb16, kb16, vb16,
                                          rTh, rTl, ipos);
    k_hash_mfma<<<dim3(BB, SS / 64), 256, 0, stream>>>(
        qk, rot, rTh, rTl, bucket_local, buckets_out);
    k_sort<<<BB * HH, 256, 0, stream>>>(bucket_local, sort_t, ipos);
    k_attn2<<<BB * NCH, 256, 0, stream>>>(qb16, kb16, vb16, sort_t, so_u, lse_u);
    k_combine2<<<(BB * SS * 8) / 256, 256, 0, stream>>>(so_u, lse_u, out_attn);
  } else {
    float* den = (float*)(sort_t + 2 * BHS);
    hipMemsetAsync(out_attn, 0, (size_t)BB * SS * DD * sizeof(float), stream);
    hipMemsetAsync(den, 0, (size_t)BB * SS * sizeof(float), stream);
    hipMemsetAsync(ipos, 0, sizeof(int), stream);
    k_hash_f32<<<dim3(BB, SS / 128), 256, 0, stream>>>(
        qk, rot, bucket_local, buckets_out, sort_t, ipos);
    k_hash_fix<<<256, 256, 0, stream>>>(qk, rot, sort_t, ipos, bucket_local,
                                        buckets_out);
    k_sort<<<BB * HH, 256, 0, stream>>>(bucket_local, sort_t, ipos);
    k_attn_atomic<<<BB * NCH, 256, 0, stream>>>(qk, v, sort_t, out_attn, den);
    k_final<<<(BB * SS * DD) / 256, 256, 0, stream>>>(out_attn, den);
  }
}

// Round 10
// 194.395 us; speedup vs baseline: 1.0317x; 1.0317x over previous
//
#include <hip/hip_runtime.h>
#include <math.h>

#define BB   16
#define SS   4096
#define DD   64
#define HH   8
#define NBH  32
#define NB   64
#define NCH  512     // global chunks per batch = HH * 64

typedef __attribute__((ext_vector_type(8))) short s16x8;   // 8 bf16
typedef __attribute__((ext_vector_type(4))) short s16x4;   // 4 bf16
typedef __attribute__((ext_vector_type(4))) float f32x4;
typedef __attribute__((ext_vector_type(4))) unsigned u32x4;

static __device__ __forceinline__ unsigned short f2bf(float x) {
  union { float f; unsigned u; } a; a.f = x;
  unsigned r = a.u + 0x7fffu + ((a.u >> 16) & 1u);   // RNE
  return (unsigned short)(r >> 16);
}
static __device__ __forceinline__ float bf2f(unsigned short u) {
  union { unsigned u; float f; } a; a.u = ((unsigned)u) << 16;
  return a.f;
}
// RNE bf16 kept in bits [31:16] (same formula as f2bf, un-shifted).
static __device__ __forceinline__ unsigned bfrnd_hi(float x) {
  union { float f; unsigned u; } a; a.f = x;
  return a.u + 0x7fffu + ((a.u >> 16) & 1u);
}
// Pack two floats as bf16 pair via v_perm byte-select. Bit-identical to
// (f2bf(lo) | f2bf(hi)<<16). Builtin, NOT inline asm (cvt_pk asm banned: R12).
static __device__ __forceinline__ unsigned pack_bf(float lo, float hi) {
  return __builtin_amdgcn_perm(bfrnd_hi(hi), bfrnd_hi(lo), 0x07060302u);
}

// ---------------------------------------------------------------------------
// Kernel 0 (R17): FUSED k_conv + k_rotT. Blocks <2048 stream fp32->bf16
// conversion; blocks >=2048 transpose rotations (b = blockIdx.x-2048).
// NOTE (R18 lesson): hipLaunchCooperativeKernel ABORTS under this harness's
// graph capture — cooperative mega-fusion is banned; 5 launches is the floor.
// ---------------------------------------------------------------------------
__global__ __launch_bounds__(256) void k_prep(
    const float* __restrict__ qk, const float* __restrict__ v,
    const float* __restrict__ rot,
    unsigned short* __restrict__ qb, unsigned short* __restrict__ kb,
    unsigned short* __restrict__ vb,
    unsigned short* __restrict__ rTh, unsigned short* __restrict__ rTl,
    int* __restrict__ needy_count) {
  __shared__ float slab[32][256];
  const int tid = threadIdx.x;

  if (blockIdx.x >= 2048) {
    // ---- rotT part ----
    const int b = blockIdx.x - 2048;
    if (b == 0 && tid == 0) *needy_count = 0;
    for (int st = 0; st < 2; st++) {
#pragma unroll
      for (int fr = 0; fr < 32; fr++)
        slab[fr][tid] = rot[(size_t)b * (DD * HH * NBH) +
                            (size_t)(st * 32 + fr) * 256 + tid];
      __syncthreads();
      unsigned short hi[32], lo[32];
#pragma unroll
      for (int fr = 0; fr < 32; fr++) {
        const float x = slab[fr][tid];
        const unsigned short hh = f2bf(x);
        hi[fr] = hh;
        lo[fr] = f2bf(x - bf2f(hh));
      }
      unsigned short* dh = rTh + ((size_t)b * 256 + tid) * DD + st * 32;
      unsigned short* dl = rTl + ((size_t)b * 256 + tid) * DD + st * 32;
#pragma unroll
      for (int g = 0; g < 4; g++) {
        *(s16x8*)(dh + g * 8) = *(const s16x8*)&hi[g * 8];
        *(s16x8*)(dl + g * 8) = *(const s16x8*)&lo[g * 8];
      }
      __syncthreads();
    }
    return;
  }

  // ---- conv part ----
  const int gid = blockIdx.x * 256 + tid;
  const int half = BB * SS * 4;
  const bool isV = gid >= half;
  const int id = isV ? gid - half : gid;
  const int row = id >> 2, q4 = id & 3;

  const float4* src =
      (const float4*)((isV ? v : qk) + (size_t)row * DD + q4 * 16);
  float vals[16];
#pragma unroll
  for (int g = 0; g < 4; g++) {
    const float4 a = src[g];
    vals[g * 4 + 0] = a.x; vals[g * 4 + 1] = a.y;
    vals[g * 4 + 2] = a.z; vals[g * 4 + 3] = a.w;
  }

  if (!isV) {
    float ss = 0.f;
#pragma unroll
    for (int i = 0; i < 16; i++) ss += vals[i] * vals[i];
    ss += __shfl_xor(ss, 1);
    ss += __shfl_xor(ss, 2);
    const float scl = 0.125f / (sqrtf(ss) + 1e-6f);
    unsigned short qo[16], ko[16];
#pragma unroll
    for (int i = 0; i < 16; i++) {
      qo[i] = f2bf(vals[i]);
      ko[i] = f2bf(vals[i] * scl);
    }
    unsigned short* qd = qb + (size_t)row * DD + q4 * 16;
    unsigned short* kd = kb + (size_t)row * DD + q4 * 16;
    *(s16x8*)qd = *(const s16x8*)&qo[0];
    *(s16x8*)(qd + 8) = *(const s16x8*)&qo[8];
    *(s16x8*)kd = *(const s16x8*)&ko[0];
    *(s16x8*)(kd + 8) = *(const s16x8*)&ko[8];
  } else {
    unsigned short vo[16];
#pragma unroll
    for (int i = 0; i < 16; i++) vo[i] = f2bf(vals[i]);
    unsigned short* vd = vb + (size_t)row * DD + q4 * 16;
    *(s16x8*)vd = *(const s16x8*)&vo[0];
    *(s16x8*)(vd + 8) = *(const s16x8*)&vo[8];
  }
}

// ---------------------------------------------------------------------------
// Kernel 1a (R17): MFMA LSH hash with FUSED needy fp64 fix.
// ---------------------------------------------------------------------------
#define MARGIN 1e-2f

__global__ __launch_bounds__(256, 4) void k_hash_mfma(
    const float* __restrict__ qk, const float* __restrict__ rot,
    const unsigned short* __restrict__ rTh,
    const unsigned short* __restrict__ rTl, int* __restrict__ bucket_local,
    float* __restrict__ buckets_out) {
  __shared__ struct __align__(16) {
    unsigned short ah[64][72];    // 9216 B
    unsigned short al[64][72];    // 9216 B
    float sc[2][64][33];          // 16896 B
    int needy[512];               // 2048 B
    int ncnt;                     // -> ~37.4 KB total, 4 blocks/CU
  } sm;
  const int b = blockIdx.x;
  const int t0 = blockIdx.y * 64;
  const int tid = threadIdx.x;
  const int w = tid >> 6, lane = tid & 63;
  const int quad = lane >> 4, l16 = lane & 15;

  if (tid == 0) sm.ncnt = 0;

  // ---- stage A hi/lo (thread = quarter token row, 16 floats) ----
  {
    const int row = tid >> 2, qf = tid & 3;
    const float4* src =
        (const float4*)(qk + ((size_t)b * SS + t0 + row) * DD + qf * 16);
#pragma unroll
    for (int gg = 0; gg < 2; gg++) {
      const float4 v0 = src[gg * 2], v1 = src[gg * 2 + 1];
      const float a[8] = {v0.x, v0.y, v0.z, v0.w, v1.x, v1.y, v1.z, v1.w};
      unsigned short hi[8], lo[8];
#pragma unroll
      for (int e = 0; e < 8; e++) {
        const unsigned short hh = f2bf(a[e]);
        hi[e] = hh;
        lo[e] = f2bf(a[e] - bf2f(hh));
      }
      *(s16x8*)&sm.ah[row][qf * 16 + gg * 8] = *(const s16x8*)hi;
      *(s16x8*)&sm.al[row][qf * 16 + gg * 8] = *(const s16x8*)lo;
    }
  }
  __syncthreads();

  // ---- hoist A-frags (wave w owns token rows w*16..w*16+15) ----
  s16x8 Ah[2], Al[2];
#pragma unroll
  for (int ks = 0; ks < 2; ks++) {
    Ah[ks] = *(const s16x8*)&sm.ah[w * 16 + l16][ks * 32 + quad * 8];
    Al[ks] = *(const s16x8*)&sm.al[w * 16 + l16][ks * 32 + quad * 8];
  }

#pragma unroll 1
  for (int h = 0; h < HH; h++) {
    const int p = h & 1;
#pragma unroll
    for (int nt = 0; nt < 2; nt++) {
      const size_t rrow = (((size_t)b * HH + h) * 32 + nt * 16 + l16) * DD;
      s16x8 Bh2[2], Bl2[2];
#pragma unroll
      for (int ks = 0; ks < 2; ks++) {
        Bh2[ks] = *(const s16x8*)&rTh[rrow + ks * 32 + quad * 8];
        Bl2[ks] = *(const s16x8*)&rTl[rrow + ks * 32 + quad * 8];
      }
      f32x4 acc = (f32x4){0.f, 0.f, 0.f, 0.f};
#pragma unroll
      for (int ks = 0; ks < 2; ks++) {
        acc = __builtin_amdgcn_mfma_f32_16x16x32_bf16(Al[ks], Bl2[ks], acc, 0, 0, 0);
        acc = __builtin_amdgcn_mfma_f32_16x16x32_bf16(Al[ks], Bh2[ks], acc, 0, 0, 0);
        acc = __builtin_amdgcn_mfma_f32_16x16x32_bf16(Ah[ks], Bl2[ks], acc, 0, 0, 0);
        acc = __builtin_amdgcn_mfma_f32_16x16x32_bf16(Ah[ks], Bh2[ks], acc, 0, 0, 0);
      }
#pragma unroll
      for (int r = 0; r < 4; r++)
        sm.sc[p][w * 16 + quad * 4 + r][nt * 16 + l16] = acc[r];
    }
    __syncthreads();

    // ---- 4-lane argmax: quad = segment {+lo,+hi,-lo,-hi}, 16 steps ----
    {
      const int tloc = w * 16 + l16;           // token within block's 64
      const float sgn = (quad >= 2) ? -1.0f : 1.0f;
      const float* rowp = &sm.sc[p][tloc][(quad & 1) * 16];
      float best = -3.0e38f, second = -3.0e38f;
      int bi = quad * 16;
#pragma unroll 8
      for (int i = 0; i < 16; i++) {
        const float vv = sgn * rowp[i];
        if (vv > best) { second = best; best = vv; bi = quad * 16 + i; }
        else if (vv > second) second = vv;
      }
      // merge level 1: xor 16 (seg pairs 0-1 and 2-3)
      {
        const float ob = __shfl_xor(best, 16);
        const float os = __shfl_xor(second, 16);
        const int obi = __shfl_xor(bi, 16);
        const float ms = fmaxf(fminf(best, ob), fmaxf(second, os));
        const bool partnerLower = (lane & 16) != 0;
        if (partnerLower ? (ob >= best) : (ob > best)) { best = ob; bi = obi; }
        second = ms;
      }
      // merge level 2: xor 32 (+half vs -half; + scanned "first")
      {
        const float ob = __shfl_xor(best, 32);
        const float os = __shfl_xor(second, 32);
        const int obi = __shfl_xor(bi, 32);
        const float ms = fmaxf(fminf(best, ob), fmaxf(second, os));
        const bool partnerLower = (lane & 32) != 0;
        if (partnerLower ? (ob >= best) : (ob > best)) { best = ob; bi = obi; }
        second = ms;
      }
      if (quad == 0) {
        const int t = t0 + tloc;
        bucket_local[((size_t)b * HH + h) * SS + t] = bi;
        buckets_out[(size_t)b * (HH * SS) + (size_t)h * SS + t] =
            (float)(h * NB + bi);
        if (best - second <= MARGIN) {
          const int slot = atomicAdd(&sm.ncnt, 1);
          sm.needy[slot] = (h << 6) | tloc;
        }
      }
    }
    // no trailing barrier: next h writes sc[1-p]; WAR on sc[p] is covered
    // by the barrier inside iteration h+1.
  }
  __syncthreads();   // needy list complete; scan global writes drained

  // ---- fused fp64 fix (identical math/structure to old k_hash_fix) ----
  const int nfix = sm.ncnt;
  const int hwid = tid >> 5;     // half-wave id 0..7
  const int li = tid & 31;
  for (int idx = hwid; idx < nfix; idx += 8) {
    const int code = sm.needy[idx];
    const int h2 = code >> 6, tloc = code & 63;
    const int t = t0 + tloc;
    const float* qrow = qk + ((size_t)b * SS + t) * DD;
    const float* rcol = rot + ((size_t)b * DD * HH + h2) * NBH + li;

    double acc = 0.0;
#pragma unroll 8
    for (int f = 0; f < DD; f++)
      acc += (double)qrow[f] * (double)rcol[(size_t)f * (HH * NBH)];

    double bv = acc;
    int bi = li;
    if (-acc > bv) { bv = -acc; bi = li + 32; }
#pragma unroll
    for (int off = 1; off < 32; off <<= 1) {
      const double ov = __shfl_xor(bv, off);
      const int oi = __shfl_xor(bi, off);
      if (ov > bv || (ov == bv && oi < bi)) { bv = ov; bi = oi; }
    }
    if (li == 0) {
      bucket_local[((size_t)b * HH + h2) * SS + t] = bi;
      buckets_out[(size_t)b * (HH * SS) + (size_t)h2 * SS + t] =
          (float)(h2 * NB + bi);
    }
  }
}

// ---------------------------------------------------------------------------
// Kernel 1b: exact fp64 recompute for near-ties (fallback path only now).
// ---------------------------------------------------------------------------
__global__ __launch_bounds__(256) void k_hash_fix(
    const float* __restrict__ qk, const float* __restrict__ rot,
    const int* __restrict__ needy_list, const int* __restrict__ needy_count,
    int* __restrict__ bucket_local, float* __restrict__ buckets_out) {
  const int n = *needy_count;
  const int hw = (blockIdx.x * 256 + (int)threadIdx.x) >> 5;
  const int li = threadIdx.x & 31;
  const int nhw = gridDim.x * 8;

  for (int idx = hw; idx < n; idx += nhw) {
    const int code = needy_list[idx];
    const int t = code & 4095;
    const int bh = code >> 12;
    const int b = bh >> 3, h = bh & 7;

    const float* qrow = qk + ((size_t)b * SS + t) * DD;
    const float* rcol = rot + ((size_t)b * DD * HH + h) * NBH + li;

    double acc = 0.0;
#pragma unroll 8
    for (int f = 0; f < DD; f++)
      acc += (double)qrow[f] * (double)rcol[(size_t)f * (HH * NBH)];

    double bv = acc;
    int bi = li;
    if (-acc > bv) { bv = -acc; bi = li + 32; }
#pragma unroll
    for (int off = 1; off < 32; off <<= 1) {
      const double ov = __shfl_xor(bv, off);
      const int oi = __shfl_xor(bi, off);
      if (ov > bv || (ov == bv && oi < bi)) { bv = ov; bi = oi; }
    }
    if (li == 0) {
      bucket_local[((size_t)b * HH + h) * SS + t] = bi;
      buckets_out[(size_t)b * (HH * SS) + (size_t)h * SS + t] =
          (float)(h * NB + bi);
    }
  }
}

// ---------------------------------------------------------------------------
// Kernel 2: parallel stable counting-rank sort per (b,h) (R17 padded).
// ---------------------------------------------------------------------------
__global__ __launch_bounds__(256) void k_sort(
    const int* __restrict__ bucket_local, int* __restrict__ sort_t,
    int* __restrict__ ipos) {
  __shared__ unsigned short lb[SS];
  __shared__ __align__(16) unsigned char cnt[NB][260];
  __shared__ __align__(16) unsigned short pfx[NB][258];
  __shared__ int part[NB][4];
  __shared__ int tot[NB];
  __shared__ int base[NB];

  const int bh = blockIdx.x;
  const int tid = threadIdx.x;
  const int* src = bucket_local + (size_t)bh * SS;

  int* czero = (int*)&cnt[0][0];
#pragma unroll
  for (int i = 0; i < 17; i++) {
    const int o = tid + i * 256;
    if (o < (NB * 260) / 4) czero[o] = 0;
  }
  __syncthreads();

#pragma unroll
  for (int i = 0; i < 16; i++) {
    const int t = tid * 16 + i;
    const int v = src[t];
    lb[t] = (unsigned short)v;
    cnt[v][tid]++;
  }
  __syncthreads();

  {
    const int bk = tid & 63, sg = tid >> 6;
    int s = 0;
#pragma unroll 8
    for (int i = 0; i < 64; i++) s += cnt[bk][sg * 64 + i];
    part[bk][sg] = s;
  }
  __syncthreads();
  if (tid < NB) tot[tid] = part[tid][0] + part[tid][1] + part[tid][2] + part[tid][3];
  __syncthreads();
  if (tid == 0) {
    int r = 0;
    for (int i = 0; i < NB; i++) { base[i] = r; r += tot[i]; }
  }
  __syncthreads();
  {
    const int bk = tid & 63, sg = tid >> 6;
    int run = base[bk];
    for (int s = 0; s < sg; s++) run += part[bk][s];
#pragma unroll 8
    for (int i = 0; i < 64; i++) {
      const int th = sg * 64 + i;
      pfx[bk][th] = (unsigned short)run;
      run += cnt[bk][th];
    }
  }
  __syncthreads();
  int* st = sort_t + (size_t)bh * SS;
#pragma unroll
  for (int i = 0; i < 16; i++) {
    const int t = tid * 16 + i;
    const int bk = lb[t];
    const int pos = pfx[bk][tid]++;
    st[pos] = t;
  }
  (void)ipos;
}

// ---------------------------------------------------------------------------
// Kernel 3: chunked attention. R20: (a) T1 XCD-aware block swizzle —
// blk = (bid&7)*1024 + bid>>3 (8192 % 8 == 0, bijective; blocks fully
// independent) so each XCD's L2 sees 2 batches (12.6 MB) instead of 16
// (100 MB) -> gather hits L2, not HBM. (b) T5 s_setprio(1) around both
// MFMA clusters (independent-block attn = m191 regime, +4-7%). Both are
// scheduling-only; all math/layout/stores byte-identical to R19.
// ---------------------------------------------------------------------------
__global__ __launch_bounds__(256, 4) void k_attn2(
    const unsigned short* __restrict__ qb, const unsigned short* __restrict__ kbg,
    const unsigned short* __restrict__ vbg, const int* __restrict__ sort_t,
    unsigned short* __restrict__ so, float* __restrict__ lse_u) {
  const int bid = blockIdx.x;
  const int blk = ((bid & 7) << 10) | (bid >> 3);   // XCD swizzle (bijective)
  const int b = blk >> 9;
  const int c = blk & 511;
  const int h = c >> 6, cc = c & 63;
  const int cp = (c + 511) & 511;
  const int hp = cp >> 6, ccp = cp & 63;

  __shared__ struct __align__(16) {
    union {
      unsigned short kb[128][72];   // K during QK^T (18432 B)
      unsigned short p[64][136];    // probs during PV (17408 B)
      float olds[64][68];           // O f32 after PV (17408 B)
    } kp;
    unsigned short vsT[64][136];    // V^T: [feature][token], 17408 B
    int tk[128];                    // 512 B -> total 36352
  } sm;

  const int tid = threadIdx.x;
  const int w = tid >> 6;
  const int lane = tid & 63;
  const int quad = lane >> 4;
  const int l16 = lane & 15;

  if (tid < 128) {
    const size_t srci = (tid < 64)
        ? (((size_t)b * HH + h) * SS + cc * 64 + tid)
        : (((size_t)b * HH + hp) * SS + ccp * 64 + (tid - 64));
    sm.tk[tid] = sort_t[srci];
  }
  __syncthreads();

  // ---- stage K row-major (2 thr/row) ----
  {
    const int j = tid >> 1, hf = tid & 1;
    const int trow = sm.tk[j];
    const s16x8* ksrc = (const s16x8*)(kbg + ((size_t)b * SS + trow) * DD + hf * 32);
    s16x8 kr[4];
#pragma unroll
    for (int g = 0; g < 4; g++) kr[g] = ksrc[g];
#pragma unroll
    for (int g = 0; g < 4; g++)
      *(s16x8*)&sm.kp.kb[j][hf * 32 + g * 8] = kr[g];
  }
  // ---- stage V transposed (thread = 4 tokens x 8 features, v_perm pack) ----
  {
    const int fg = tid >> 5;          // 0..7  feature group (8 feats)
    const int tg = (tid & 31) << 2;   // 0,4,...,124 token base
    const unsigned short* vb_b = vbg + (size_t)b * SS * DD + fg * 8;
    const u32x4 a0v = *(const u32x4*)(vb_b + (size_t)sm.tk[tg + 0] * DD);
    const u32x4 a1v = *(const u32x4*)(vb_b + (size_t)sm.tk[tg + 1] * DD);
    const u32x4 a2v = *(const u32x4*)(vb_b + (size_t)sm.tk[tg + 2] * DD);
    const u32x4 a3v = *(const u32x4*)(vb_b + (size_t)sm.tk[tg + 3] * DD);
#pragma unroll
    for (int j = 0; j < 4; j++) {
      uint2 ev, ov;
      ev.x = __builtin_amdgcn_perm(a1v[j], a0v[j], 0x05040100u);
      ev.y = __builtin_amdgcn_perm(a3v[j], a2v[j], 0x05040100u);
      ov.x = __builtin_amdgcn_perm(a1v[j], a0v[j], 0x07060302u);
      ov.y = __builtin_amdgcn_perm(a3v[j], a2v[j], 0x07060302u);
      *(uint2*)&sm.vsT[fg * 8 + 2 * j][tg] = ev;
      *(uint2*)&sm.vsT[fg * 8 + 2 * j + 1][tg] = ov;
    }
  }
  // ---- Q B-frags direct from global (tk valid after first barrier) ----
  const int tq = sm.tk[w * 16 + l16];
  const unsigned short* qrowp = qb + ((size_t)b * SS + tq) * DD;
  const s16x8 a0 = *(const s16x8*)(qrowp + quad * 8);
  const s16x8 a1 = *(const s16x8*)(qrowp + 32 + quad * 8);
  __syncthreads();

  // ---- QK^T swapped: acc[nt] holds S[q = w*16+l16][k = nt*16+quad*4+r] ----
  f32x4 acc[8];
#pragma unroll
  for (int nt = 0; nt < 8; nt++) acc[nt] = (f32x4){0.f, 0.f, 0.f, 0.f};
  __builtin_amdgcn_s_setprio(1);
#pragma unroll
  for (int nt = 0; nt < 8; nt++) {
    const s16x8 b0 = *(const s16x8*)&sm.kp.kb[nt * 16 + l16][quad * 8];
    const s16x8 b1 = *(const s16x8*)&sm.kp.kb[nt * 16 + l16][32 + quad * 8];
    acc[nt] = __builtin_amdgcn_mfma_f32_16x16x32_bf16(b0, a0, acc[nt], 0, 0, 0);
    acc[nt] = __builtin_amdgcn_mfma_f32_16x16x32_bf16(b1, a1, acc[nt], 0, 0, 0);
  }
  __builtin_amdgcn_s_setprio(0);

  // ---- self-mask (index-based, S^T layout) ----
  {
    const bool dm = (quad == (l16 >> 2));
    const int rm = l16 & 3;
#pragma unroll
    for (int nt = 0; nt < 4; nt++)
      if (nt == w) {
#pragma unroll
        for (int r = 0; r < 4; r++)
          if (dm && rm == r) acc[nt][r] = -50000.0f;
      }
  }
  if (cc == 0) {     // look-back crosses hash rounds: token ids can repeat
#pragma unroll
    for (int nt = 4; nt < 8; nt++)
#pragma unroll
      for (int r = 0; r < 4; r++)
        if (sm.tk[nt * 16 + quad * 4 + r] == tq) acc[nt][r] = -50000.0f;
  }

  // ---- scalar row softmax (in-lane 32 + shfl 16,32) ----
  float mv[8];
#pragma unroll
  for (int nt = 0; nt < 8; nt++)
    mv[nt] = fmaxf(fmaxf(acc[nt][0], acc[nt][1]), fmaxf(acc[nt][2], acc[nt][3]));
  float m = fmaxf(fmaxf(fmaxf(mv[0], mv[1]), fmaxf(mv[2], mv[3])),
                  fmaxf(fmaxf(mv[4], mv[5]), fmaxf(mv[6], mv[7])));
  m = fmaxf(m, __shfl_xor(m, 16));
  m = fmaxf(m, __shfl_xor(m, 32));

  float sv[8];
#pragma unroll
  for (int nt = 0; nt < 8; nt++) {
#pragma unroll
    for (int r = 0; r < 4; r++) acc[nt][r] = __expf(acc[nt][r] - m);
    sv[nt] = (acc[nt][0] + acc[nt][1]) + (acc[nt][2] + acc[nt][3]);
  }
  float s = ((sv[0] + sv[1]) + (sv[2] + sv[3])) +
            ((sv[4] + sv[5]) + (sv[6] + sv[7]));
  s += __shfl_xor(s, 16);
  s += __shfl_xor(s, 32);
  const float inv = 1.0f / s;
  const float lse = __logf(s) + m;

  if (quad == 0)
    lse_u[((size_t)b * SS + tq) * HH + h] = lse;

  __syncthreads();   // all kb reads done -> safe to overwrite with p

  // ---- stage probs bf16: lane writes its 4 consecutive k-cols per nt ----
  {
    const int prow = w * 16 + l16;
#pragma unroll
    for (int nt = 0; nt < 8; nt++) {
      uint2 pv;
      pv.x = pack_bf(acc[nt][0] * inv, acc[nt][1] * inv);
      pv.y = pack_bf(acc[nt][2] * inv, acc[nt][3] * inv);
      *(uint2*)&sm.kp.p[prow][nt * 16 + quad * 4] = pv;
    }
  }
  __syncthreads();

  // ---- PV as O^T = V^T * P^T (both operands ds_read_b128) ----
  f32x4 o[4];
#pragma unroll
  for (int nt = 0; nt < 4; nt++) o[nt] = (f32x4){0.f, 0.f, 0.f, 0.f};
  const unsigned short* vrow = &sm.vsT[w * 16 + l16][0];
  __builtin_amdgcn_s_setprio(1);
#pragma unroll
  for (int kc = 0; kc < 4; kc++) {
    const s16x8 av = *(const s16x8*)(vrow + kc * 32 + quad * 8);
#pragma unroll
    for (int nt = 0; nt < 4; nt++) {
      const s16x8 bp = *(const s16x8*)&sm.kp.p[nt * 16 + l16][kc * 32 + quad * 8];
      o[nt] = __builtin_amdgcn_mfma_f32_16x16x32_bf16(av, bp, o[nt], 0, 0, 0);
    }
  }
  __builtin_amdgcn_s_setprio(0);

  __syncthreads();   // all p reads done -> safe to overwrite with olds

  // ---- park O in LDS f32: lane holds q = nt*16+l16, f = w*16+quad*4..+3 ----
#pragma unroll
  for (int nt = 0; nt < 4; nt++)
    *(f32x4*)&sm.kp.olds[nt * 16 + l16][w * 16 + quad * 4] = o[nt];
  __syncthreads();

  // ---- coalesced store: 4 threads/token emit the full 128B row ----
  {
    const int q = tid >> 2, qt = tid & 3;
    const int t = sm.tk[q];
    float vals[16];
    *(f32x4*)&vals[0]  = *(const f32x4*)&sm.kp.olds[q][qt * 16 + 0];
    *(f32x4*)&vals[4]  = *(const f32x4*)&sm.kp.olds[q][qt * 16 + 4];
    *(f32x4*)&vals[8]  = *(const f32x4*)&sm.kp.olds[q][qt * 16 + 8];
    *(f32x4*)&vals[12] = *(const f32x4*)&sm.kp.olds[q][qt * 16 + 12];
    unsigned pk[8];
#pragma unroll
    for (int g = 0; g < 8; g++) pk[g] = pack_bf(vals[2 * g], vals[2 * g + 1]);
    unsigned short* dst =
        so + (((size_t)b * SS + t) * HH + h) * DD + qt * 16;
    *(uint4*)dst = *(const uint4*)&pk[0];
    *(uint4*)(dst + 8) = *(const uint4*)&pk[4];
  }
}

// ---------------------------------------------------------------------------
// Kernel 4: streaming combine over hashes (R16 vectorized, unchanged).
// ---------------------------------------------------------------------------
__global__ __launch_bounds__(256) void k_combine2(
    const unsigned short* __restrict__ so, const float* __restrict__ lse_u,
    float* __restrict__ out) {
  const size_t idx = (size_t)blockIdx.x * 256 + threadIdx.x;
  const int fg = (int)(idx & 7);           // feature group of 8
  const size_t bt = idx >> 3;

  const float4 l0 = *(const float4*)(lse_u + bt * HH);
  const float4 l1 = *(const float4*)(lse_u + bt * HH + 4);
  const float l[HH] = {l0.x, l0.y, l0.z, l0.w, l1.x, l1.y, l1.z, l1.w};
  float m = l[0];
#pragma unroll
  for (int h = 1; h < HH; h++) m = fmaxf(m, l[h]);

  float den = 0.f;
  float num[8];
#pragma unroll
  for (int e = 0; e < 8; e++) num[e] = 0.f;
#pragma unroll
  for (int h = 0; h < HH; h++) {
    const float wgt = __expf(l[h] - m);
    den += wgt;
    const s16x8 v = *(const s16x8*)(so + (bt * HH + h) * DD + fg * 8);
#pragma unroll
    for (int e = 0; e < 8; e++)
      num[e] += wgt * bf2f((unsigned short)v[e]);
  }

  float4 o0, o1;
  o0.x = num[0] / den; o0.y = num[1] / den;
  o0.z = num[2] / den; o0.w = num[3] / den;
  o1.x = num[4] / den; o1.y = num[5] / den;
  o1.z = num[6] / den; o1.w = num[7] / den;
  float* dst = out + bt * DD + fg * 8;
  *(float4*)dst = o0;
  *(float4*)(dst + 4) = o1;
}

// ---------------------------------------------------------------------------
// Fallback-path hash (R8's fp32) + atomic attention (R1-proven).
// ---------------------------------------------------------------------------
__global__ __launch_bounds__(256, 2) void k_hash_f32(
    const float* __restrict__ qk, const float* __restrict__ rot,
    int* __restrict__ bucket_local, float* __restrict__ buckets_out,
    int* __restrict__ needy_list, int* __restrict__ needy_count) {
  __shared__ float lb[128 * 65];
  const int b = blockIdx.x;
  const int t0 = blockIdx.y * 128;
  const int tid = threadIdx.x;

  {
    const int row = tid >> 1, hf = (tid & 1) * 32;
    const float4* src =
        (const float4*)(qk + ((size_t)b * SS + t0 + row) * DD + hf);
    float* dst = &lb[row * 65 + hf];
#pragma unroll
    for (int g = 0; g < 8; g++) {
      const float4 vv = src[g];
      dst[g * 4 + 0] = vv.x; dst[g * 4 + 1] = vv.y;
      dst[g * 4 + 2] = vv.z; dst[g * 4 + 3] = vv.w;
    }
  }
  __syncthreads();

  const int w = tid >> 6;
  const int l = tid & 63;
  const int hb = __builtin_amdgcn_readfirstlane(w);

  for (int hp = 0; hp < 2; hp++) {
    const int h = hb + hp * 4;
    const float* rbase = rot + ((size_t)b * DD * HH + h) * NBH;
    const size_t rstride = HH * NBH;

    float acc0[NBH], acc1[NBH];
#pragma unroll
    for (int i = 0; i < NBH; i++) { acc0[i] = 0.f; acc1[i] = 0.f; }

    float4 bufA[8], bufB[8];
#pragma unroll
    for (int i4 = 0; i4 < 8; i4++) bufA[i4] = ((const float4*)rbase)[i4];

    for (int f = 0; f < DD; f += 2) {
      {
        const float4* r4 = (const float4*)(rbase + (size_t)(f + 1) * rstride);
#pragma unroll
        for (int i4 = 0; i4 < 8; i4++) bufB[i4] = r4[i4];
      }
      {
        const float q0 = lb[l * 65 + f];
        const float q1 = lb[(l + 64) * 65 + f];
#pragma unroll
        for (int i4 = 0; i4 < 8; i4++) {
          const float4 rv = bufA[i4];
          acc0[i4*4+0] = fmaf(q0, rv.x, acc0[i4*4+0]);
          acc0[i4*4+1] = fmaf(q0, rv.y, acc0[i4*4+1]);
          acc0[i4*4+2] = fmaf(q0, rv.z, acc0[i4*4+2]);
          acc0[i4*4+3] = fmaf(q0, rv.w, acc0[i4*4+3]);
          acc1[i4*4+0] = fmaf(q1, rv.x, acc1[i4*4+0]);
          acc1[i4*4+1] = fmaf(q1, rv.y, acc1[i4*4+1]);
          acc1[i4*4+2] = fmaf(q1, rv.z, acc1[i4*4+2]);
          acc1[i4*4+3] = fmaf(q1, rv.w, acc1[i4*4+3]);
        }
      }
      if (f + 2 < DD) {
        const float4* r4 = (const float4*)(rbase + (size_t)(f + 2) * rstride);
#pragma unroll
        for (int i4 = 0; i4 < 8; i4++) bufA[i4] = r4[i4];
      }
      {
        const float q0 = lb[l * 65 + f + 1];
        const float q1 = lb[(l + 64) * 65 + f + 1];
#pragma unroll
        for (int i4 = 0; i4 < 8; i4++) {
          const float4 rv = bufB[i4];
          acc0[i4*4+0] = fmaf(q0, rv.x, acc0[i4*4+0]);
          acc0[i4*4+1] = fmaf(q0, rv.y, acc0[i4*4+1]);
          acc0[i4*4+2] = fmaf(q0, rv.z, acc0[i4*4+2]);
          acc0[i4*4+3] = fmaf(q0, rv.w, acc0[i4*4+3]);
          acc1[i4*4+0] = fmaf(q1, rv.x, acc1[i4*4+0]);
          acc1[i4*4+1] = fmaf(q1, rv.y, acc1[i4*4+1]);
          acc1[i4*4+2] = fmaf(q1, rv.z, acc1[i4*4+2]);
          acc1[i4*4+3] = fmaf(q1, rv.w, acc1[i4*4+3]);
        }
      }
    }

#pragma unroll
    for (int tok = 0; tok < 2; tok++) {
      const float* acc = tok ? acc1 : acc0;
      float best = -3.0e38f, second = -3.0e38f;
      int bi = 0;
#pragma unroll
      for (int i = 0; i < 64; i++) {
        const float vv = (i < NBH) ? acc[i] : -acc[i - NBH];
        if (vv > best) { second = best; best = vv; bi = i; }
        else if (vv > second) { second = vv; }
      }
      const int t = t0 + tok * 64 + l;
      bucket_local[((size_t)b * HH + h) * SS + t] = bi;
      buckets_out[(size_t)b * (HH * SS) + (size_t)h * SS + t] =
          (float)(h * NB + bi);
      if (best - second <= MARGIN) {
        const int slot = atomicAdd(needy_count, 1);
        needy_list[slot] = (((b << 3) | h) << 12) | t;
      }
    }
  }
}

__global__ __launch_bounds__(256) void k_attn_atomic(
    const float* __restrict__ qk, const float* __restrict__ v,
    const int* __restrict__ sort_t, float* __restrict__ num,
    float* __restrict__ den) {
  const int blk = blockIdx.x;
  const int b = blk >> 9;
  const int c = blk & 511;
  const int h = c >> 6, cc = c & 63;
  const int cp = (c + 511) & 511;
  const int hp = cp >> 6, ccp = cp & 63;

  __shared__ union {
    struct {
      float qt[DD * 64];
      float kt[DD * 128];
      int   tq[64];
      int   tk[128];
      float nrm[128];
      float red[16 * 64];
      float rmax[64];
      float rsum[64];
    } a;
    struct {
      float pt[128 * 64];
      float vs[128 * 64];
    } p;
  } sm;

  const int tid = threadIdx.x;

  if (tid < 64)
    sm.a.tq[tid] = sort_t[((size_t)b * HH + h) * SS + cc * 64 + tid];
  if (tid >= 128) {
    const int j = tid - 128;
    const size_t src = (j < 64) ? (((size_t)b * HH + h) * SS + cc * 64 + j)
                                : (((size_t)b * HH + hp) * SS + ccp * 64 + (j - 64));
    sm.a.tk[j] = sort_t[src];
  }
  if (tid >= 64 && tid < 192) sm.a.nrm[tid - 64] = 0.f;
  __syncthreads();

  {
    const int qi = tid >> 2, qq = tid & 3;
    const float4* qsrc =
        (const float4*)(qk + ((size_t)b * SS + sm.a.tq[qi]) * DD) + qq * 4;
#pragma unroll
    for (int k4 = 0; k4 < 4; k4++) {
      float4 val = qsrc[k4];
      const int f = qq * 16 + k4 * 4;
      sm.a.qt[(f + 0) * 64 + qi] = val.x;
      sm.a.qt[(f + 1) * 64 + qi] = val.y;
      sm.a.qt[(f + 2) * 64 + qi] = val.z;
      sm.a.qt[(f + 3) * 64 + qi] = val.w;
    }
    const int j = tid >> 1, hhf = tid & 1;
    const float4* ksrc =
        (const float4*)(qk + ((size_t)b * SS + sm.a.tk[j]) * DD) + hhf * 8;
    float ss = 0.f;
#pragma unroll
    for (int k4 = 0; k4 < 8; k4++) {
      float4 val = ksrc[k4];
      const int f = hhf * 32 + k4 * 4;
      sm.a.kt[(f + 0) * 128 + j] = val.x;
      sm.a.kt[(f + 1) * 128 + j] = val.y;
      sm.a.kt[(f + 2) * 128 + j] = val.z;
      sm.a.kt[(f + 3) * 128 + j] = val.w;
      ss += val.x * val.x + val.y * val.y + val.z * val.z + val.w * val.w;
    }
    atomicAdd(&sm.a.nrm[j], ss);
  }
  __syncthreads();
  if (tid < 128) {
    const float n = sqrtf(sm.a.nrm[tid]) + 1e-6f;
    sm.a.nrm[tid] = 0.125f / n;
  }
  float4 vreg[8];
  {
    const int j = tid >> 1, hhf = tid & 1;
    const float4* vsrc =
        (const float4*)(v + ((size_t)b * SS + sm.a.tk[j]) * DD) + hhf * 8;
#pragma unroll
    for (int k4 = 0; k4 < 8; k4++) vreg[k4] = vsrc[k4];
  }
  __syncthreads();

  const int qi0 = (tid & 15) * 4;
  const int j0g = (tid >> 4) * 8;
  const int kg = tid >> 4;
  float acc[4][8];
#pragma unroll
  for (int i = 0; i < 4; i++)
#pragma unroll
    for (int j = 0; j < 8; j++) acc[i][j] = 0.f;

#pragma unroll 8
  for (int f = 0; f < DD; f++) {
    float4 qv = *(const float4*)&sm.a.qt[f * 64 + qi0];
    float4 k0 = *(const float4*)&sm.a.kt[f * 128 + j0g];
    float4 k1 = *(const float4*)&sm.a.kt[f * 128 + j0g + 4];
    float qa[4] = {qv.x, qv.y, qv.z, qv.w};
    float ka[8] = {k0.x, k0.y, k0.z, k0.w, k1.x, k1.y, k1.z, k1.w};
#pragma unroll
    for (int i = 0; i < 4; i++)
#pragma unroll
      for (int j = 0; j < 8; j++) acc[i][j] = fmaf(qa[i], ka[j], acc[i][j]);
  }

  int tqr[4];
#pragma unroll
  for (int i = 0; i < 4; i++) tqr[i] = sm.a.tq[qi0 + i];
  int tkr[8]; float scl[8];
#pragma unroll
  for (int j = 0; j < 8; j++) {
    tkr[j] = sm.a.tk[j0g + j];
    scl[j] = sm.a.nrm[j0g + j];
  }
#pragma unroll
  for (int i = 0; i < 4; i++)
#pragma unroll
    for (int j = 0; j < 8; j++) {
      const float dv = acc[i][j] * scl[j];
      acc[i][j] = (tqr[i] == tkr[j]) ? -50000.0f : dv;
    }

  float pmax[4];
#pragma unroll
  for (int i = 0; i < 4; i++) {
    float m = acc[i][0];
#pragma unroll
    for (int j = 1; j < 8; j++) m = fmaxf(m, acc[i][j]);
    pmax[i] = m;
  }
#pragma unroll
  for (int i = 0; i < 4; i++) sm.a.red[kg * 64 + qi0 + i] = pmax[i];
  __syncthreads();
  if (tid < 64) {
    float m = -3.0e38f;
#pragma unroll
    for (int g = 0; g < 16; g++) m = fmaxf(m, sm.a.red[g * 64 + tid]);
    sm.a.rmax[tid] = m;
  }
  __syncthreads();
  float psum[4];
#pragma unroll
  for (int i = 0; i < 4; i++) {
    const float rm = sm.a.rmax[qi0 + i];
    float s = 0.f;
#pragma unroll
    for (int j = 0; j < 8; j++) {
      const float e = __expf(acc[i][j] - rm);
      acc[i][j] = e;
      s += e;
    }
    psum[i] = s;
  }
#pragma unroll
  for (int i = 0; i < 4; i++) sm.a.red[kg * 64 + qi0 + i] = psum[i];
  __syncthreads();
  if (tid < 64) {
    float s = 0.f;
#pragma unroll
    for (int g = 0; g < 16; g++) s += sm.a.red[g * 64 + tid];
    sm.a.rsum[tid] = s;
  }
  __syncthreads();
  float lse[4], isum[4];
#pragma unroll
  for (int i = 0; i < 4; i++) {
    const float rm = sm.a.rmax[qi0 + i];
    const float s = sm.a.rsum[qi0 + i];
    isum[i] = 1.0f / s;
    lse[i] = __logf(s) + rm;
  }
  __syncthreads();

#pragma unroll
  for (int j = 0; j < 8; j++)
#pragma unroll
    for (int i = 0; i < 4; i++)
      sm.p.pt[(j0g + j) * 64 + qi0 + i] = acc[i][j] * isum[i];
  {
    const int j = tid >> 1, hhf = tid & 1;
#pragma unroll
    for (int k4 = 0; k4 < 8; k4++)
      *(float4*)&sm.p.vs[j * 64 + hhf * 32 + k4 * 4] = vreg[k4];
  }
  __syncthreads();

  const int f0 = (tid >> 4) * 4;
  float o[4][4];
#pragma unroll
  for (int i = 0; i < 4; i++)
#pragma unroll
    for (int j = 0; j < 4; j++) o[i][j] = 0.f;

#pragma unroll 8
  for (int j = 0; j < 128; j++) {
    float4 pv = *(const float4*)&sm.p.pt[j * 64 + qi0];
    float4 vv = *(const float4*)&sm.p.vs[j * 64 + f0];
    float pa[4] = {pv.x, pv.y, pv.z, pv.w};
    float va[4] = {vv.x, vv.y, vv.z, vv.w};
#pragma unroll
    for (int i = 0; i < 4; i++)
#pragma unroll
      for (int j2 = 0; j2 < 4; j2++) o[i][j2] = fmaf(pa[i], va[j2], o[i][j2]);
  }

#pragma unroll
  for (int i = 0; i < 4; i++) {
    const float w = __expf(lse[i]);
    float* dst = num + ((size_t)b * SS + tqr[i]) * DD + f0;
#pragma unroll
    for (int j = 0; j < 4; j++) atomicAdd(dst + j, o[i][j] * w);
    if (kg == 0) atomicAdd(den + (size_t)b * SS + tqr[i], w);
  }
}

__global__ __launch_bounds__(256) void k_final(float* __restrict__ o,
                                               const float* __restrict__ den) {
  const size_t i = (size_t)blockIdx.x * 256 + threadIdx.x;
  o[i] = o[i] / den[i >> 6];
}

extern "C" void kernel_launch(void* const* d_in, const int* in_sizes, int n_in,
                              void* d_out, int out_size, void* d_ws,
                              size_t ws_size, hipStream_t stream) {
  const float* qk  = (const float*)d_in[0];
  const float* v   = (const float*)d_in[1];
  const float* rot = (const float*)d_in[2];

  float* out_attn = (float*)d_out;                      // B*S*D floats
  float* buckets_out = out_attn + (size_t)BB * SS * DD; // B*H*S floats

  const size_t BHS = (size_t)BB * HH * SS;              // 524288
  const size_t BSD = (size_t)BB * SS * DD;              // 4194304
  const size_t RT  = (size_t)BB * HH * 32 * DD;         // 262144
  int* bucket_local = (int*)d_ws;
  int* sort_t = bucket_local + BHS;                     // doubles as needy_list
  int* ipos = sort_t + BHS;                             // ipos[0] = needy_count
  float* lse_u = (float*)(ipos + BHS);                  // [b][t][h]
  unsigned short* qb16 = (unsigned short*)(lse_u + BHS);
  unsigned short* kb16 = qb16 + BSD;
  unsigned short* vb16 = kb16 + BSD;
  unsigned short* so_u = vb16 + BSD;                    // [b][t][h][f] bf16
  unsigned short* rTh = so_u + BHS * DD;
  unsigned short* rTl = rTh + RT;

  const size_t NEED2 =
      4 * BHS * 4 + 3 * BSD * 2 + BHS * DD * 2 + 2 * RT * 2;  // ~101.7 MB

  if (ws_size >= NEED2) {
    k_prep<<<2048 + BB, 256, 0, stream>>>(qk, v, rot, qb16, kb16, vb16,
                                          rTh, rTl, ipos);
    k_hash_mfma<<<dim3(BB, SS / 64), 256, 0, stream>>>(
        qk, rot, rTh, rTl, bucket_local, buckets_out);
    k_sort<<<BB * HH, 256, 0, stream>>>(bucket_local, sort_t, ipos);
    k_attn2<<<BB * NCH, 256, 0, stream>>>(qb16, kb16, vb16, sort_t, so_u, lse_u);
    k_combine2<<<(BB * SS * 8) / 256, 256, 0, stream>>>(so_u, lse_u, out_attn);
  } else {
    float* den = (float*)(sort_t + 2 * BHS);
    hipMemsetAsync(out_attn, 0, (size_t)BB * SS * DD * sizeof(float), stream);
    hipMemsetAsync(den, 0, (size_t)BB * SS * sizeof(float), stream);
    hipMemsetAsync(ipos, 0, sizeof(int), stream);
    k_hash_f32<<<dim3(BB, SS / 128), 256, 0, stream>>>(
        qk, rot, bucket_local, buckets_out, sort_t, ipos);
    k_hash_fix<<<256, 256, 0, stream>>>(qk, rot, sort_t, ipos, bucket_local,
                                        buckets_out);
    k_sort<<<BB * HH, 256, 0, stream>>>(bucket_local, sort_t, ipos);
    k_attn_atomic<<<BB * NCH, 256, 0, stream>>>(qk, v, sort_t, out_attn, den);
    k_final<<<(BB * SS * DD) / 256, 256, 0, stream>>>(out_attn, den);
  }
}